// Round 1
// baseline (557.250 us; speedup 1.0000x reference)
//
#include <hip/hip_runtime.h>
#include <stdint.h>

typedef unsigned short u16;
typedef __bf16 bf16x8 __attribute__((ext_vector_type(8)));
typedef unsigned short u16x8 __attribute__((ext_vector_type(8)));
typedef float f32x4 __attribute__((ext_vector_type(4)));

#define SCALE_QK 0.125f

__device__ __forceinline__ u16 f2bf(float f) {
    uint32_t u = __builtin_bit_cast(uint32_t, f);
    u += 0x7FFFu + ((u >> 16) & 1u);
    return (u16)(u >> 16);
}

// ---------------- f32 -> bf16 convert, 4 elems/thread ----------------
__global__ void cvt_f32_bf16(const float* __restrict__ src, u16* __restrict__ dst, int n4) {
    int i = blockIdx.x * blockDim.x + threadIdx.x;
    if (i >= n4) return;
    float4 v = ((const float4*)src)[i];
    ushort4 o;
    o.x = f2bf(v.x); o.y = f2bf(v.y); o.z = f2bf(v.z); o.w = f2bf(v.w);
    ((ushort4*)dst)[i] = o;
}

// ---------------- mask -> additive f32 bias (0 / -1e30) ----------------
// Defensive: detect byte-bool vs int32 storage (all-ones bool bytes read as
// int32 give 0x01010101; int32 ones give 1).
__global__ void mask_prep(const int* __restrict__ maski, float* __restrict__ mb, int n) {
    int i = blockIdx.x * blockDim.x + threadIdx.x;
    if (i >= n) return;
    int v0 = maski[0];
    int v = (v0 == 0x01010101) ? (int)((const unsigned char*)maski)[i] : maski[i];
    mb[i] = v ? 0.0f : -1e30f;
}

// ---------------- GEMM: C[M,N] = A[M,K] * Bt[N,K]^T + bias ----------------
// m97 structure: 128x128 tile, BK=32, 4 waves (2x2 of 64x64), global_load_lds w16.
__device__ __forceinline__ void gload_lds16(const void* g, void* l) {
    __builtin_amdgcn_global_load_lds(
        (__attribute__((address_space(1))) void*)(g),
        (__attribute__((address_space(3))) void*)(l), 16, 0, 0);
}

template<int OUT_BF16>
__global__ __launch_bounds__(256)
void gemm_bt(const u16* __restrict__ A, const u16* __restrict__ Bt,
             const float* __restrict__ bias, void* __restrict__ Cout,
             int M, int N, int K, int ldc) {
    __shared__ u16 As[128 * 32];
    __shared__ u16 Bs[128 * 32];
    const int tid = threadIdx.x;
    const int wid = tid >> 6, lane = tid & 63;
    const int lo = lane & 15, hi = lane >> 4;
    const int wr = wid >> 1, wc = wid & 1;
    const int bm = blockIdx.y, bn = blockIdx.x;
    const u16* Ab = A + (size_t)bm * 128 * K;
    const u16* Bb = Bt + (size_t)bn * 128 * K;
    f32x4 acc[4][4] = {};
    for (int k0 = 0; k0 < K; k0 += 32) {
#pragma unroll
        for (int it = 0; it < 2; ++it) {
            int eo = it * 2048 + wid * 512 + lane * 8;   // element offset in tile
            int row = eo >> 5, kk = eo & 31;
            gload_lds16(Ab + (size_t)row * K + k0 + kk, As + it * 2048 + wid * 512);
            gload_lds16(Bb + (size_t)row * K + k0 + kk, Bs + it * 2048 + wid * 512);
        }
        __syncthreads();
        bf16x8 af[4], bfr[4];
        const int koff = hi * 8;
#pragma unroll
        for (int m = 0; m < 4; ++m)
            af[m] = *(const bf16x8*)(As + (wr * 64 + m * 16 + lo) * 32 + koff);
#pragma unroll
        for (int n = 0; n < 4; ++n)
            bfr[n] = *(const bf16x8*)(Bs + (wc * 64 + n * 16 + lo) * 32 + koff);
#pragma unroll
        for (int m = 0; m < 4; ++m)
#pragma unroll
            for (int n = 0; n < 4; ++n)
                acc[m][n] = __builtin_amdgcn_mfma_f32_16x16x32_bf16(af[m], bfr[n], acc[m][n], 0, 0, 0);
        __syncthreads();
    }
    const int rowbase = bm * 128 + wr * 64, colbase = bn * 128 + wc * 64;
#pragma unroll
    for (int m = 0; m < 4; ++m) {
#pragma unroll
        for (int n = 0; n < 4; ++n) {
            int col = colbase + n * 16 + lo;
            int row0 = rowbase + m * 16 + hi * 4;
            float bv = bias[col];
#pragma unroll
            for (int r = 0; r < 4; ++r) {
                float v = acc[m][n][r] + bv;
                if (OUT_BF16) ((u16*)Cout)[(size_t)(row0 + r) * ldc + col] = f2bf(v);
                else ((float*)Cout)[(size_t)(row0 + r) * ldc + col] = v;
            }
        }
    }
}

// ---------------- fused flash attention ----------------
// Qbuf: [B*Sq][3072], q at cols 0..1023. KVbuf: [B*Sk][3072], k at 1024.., v at 2048..
// Out: [B*Sq][1024]. Grid: (Sq/64, B*H). 4 waves, 16 q-rows each, 32-key chunks.
template<int MASKED>
__global__ __launch_bounds__(256)
void attn_fwd(const u16* __restrict__ Qbuf, const u16* __restrict__ KVbuf,
              const float* __restrict__ mb, u16* __restrict__ Out,
              int Sq, int Sk) {
    __shared__ u16 p_lds[4][16 * 32];
    const int tid = threadIdx.x, wid = tid >> 6, lane = tid & 63;
    const int lo = lane & 15, hi = lane >> 4;
    const int b = blockIdx.y >> 4, h = blockIdx.y & 15;
    const int qbase = b * Sq + blockIdx.x * 64 + wid * 16;
    const u16* Qp = Qbuf + (size_t)qbase * 3072 + h * 64;
    const u16* Kp = KVbuf + (size_t)b * Sk * 3072 + 1024 + h * 64;
    const u16* Vp = KVbuf + (size_t)b * Sk * 3072 + 2048 + h * 64;
    bf16x8 qf[2];
#pragma unroll
    for (int ks = 0; ks < 2; ++ks)
        qf[ks] = *(const bf16x8*)(Qp + (size_t)lo * 3072 + ks * 32 + hi * 8);
    f32x4 oacc[4] = {};
    float mrow[4], lrow[4];
#pragma unroll
    for (int r = 0; r < 4; ++r) { mrow[r] = -3e38f; lrow[r] = 0.f; }
    u16* pl = p_lds[wid];
    for (int c0 = 0; c0 < Sk; c0 += 32) {
        float sc[2][4];
#pragma unroll
        for (int kt = 0; kt < 2; ++kt) {
            const u16* kp = Kp + (size_t)(c0 + kt * 16 + lo) * 3072 + hi * 8;
            bf16x8 kf0 = *(const bf16x8*)(kp);
            bf16x8 kf1 = *(const bf16x8*)(kp + 32);
            f32x4 z = {};
            z = __builtin_amdgcn_mfma_f32_16x16x32_bf16(qf[0], kf0, z, 0, 0, 0);
            z = __builtin_amdgcn_mfma_f32_16x16x32_bf16(qf[1], kf1, z, 0, 0, 0);
            float mbv = 0.f;
            if (MASKED) mbv = mb[b * Sk + c0 + kt * 16 + lo];
#pragma unroll
            for (int r = 0; r < 4; ++r) sc[kt][r] = z[r] * SCALE_QK + mbv;
        }
        float alpha[4];
#pragma unroll
        for (int r = 0; r < 4; ++r) {
            float v = fmaxf(sc[0][r], sc[1][r]);
            v = fmaxf(v, __shfl_xor(v, 1));
            v = fmaxf(v, __shfl_xor(v, 2));
            v = fmaxf(v, __shfl_xor(v, 4));
            v = fmaxf(v, __shfl_xor(v, 8));
            float mn = fmaxf(mrow[r], v);
            alpha[r] = __expf(mrow[r] - mn);
            mrow[r] = mn;
        }
#pragma unroll
        for (int r = 0; r < 4; ++r) {
            float p0 = __expf(sc[0][r] - mrow[r]);
            float p1 = __expf(sc[1][r] - mrow[r]);
            sc[0][r] = p0; sc[1][r] = p1;
            float v = p0 + p1;
            v += __shfl_xor(v, 1);
            v += __shfl_xor(v, 2);
            v += __shfl_xor(v, 4);
            v += __shfl_xor(v, 8);
            lrow[r] = lrow[r] * alpha[r] + v;
        }
#pragma unroll
        for (int n = 0; n < 4; ++n)
#pragma unroll
            for (int r = 0; r < 4; ++r) oacc[n][r] *= alpha[r];
        // P (C-frag layout) -> LDS [16q][32p] -> A-frag
#pragma unroll
        for (int kt = 0; kt < 2; ++kt)
#pragma unroll
            for (int r = 0; r < 4; ++r)
                pl[(hi * 4 + r) * 32 + kt * 16 + lo] = f2bf(sc[kt][r]);
        __syncthreads();
        bf16x8 pf = *(const bf16x8*)(pl + lo * 32 + hi * 8);
        __syncthreads();
#pragma unroll
        for (int n = 0; n < 4; ++n) {
            const u16* vp = Vp + (size_t)(c0 + hi * 8) * 3072 + n * 16 + lo;
            u16x8 vraw;
#pragma unroll
            for (int jj = 0; jj < 8; ++jj)
                vraw[jj] = vp[(size_t)jj * 3072];
            bf16x8 vf = __builtin_bit_cast(bf16x8, vraw);
            oacc[n] = __builtin_amdgcn_mfma_f32_16x16x32_bf16(pf, vf, oacc[n], 0, 0, 0);
        }
    }
    float inv[4];
#pragma unroll
    for (int r = 0; r < 4; ++r) inv[r] = 1.0f / lrow[r];
    u16* op = Out + (size_t)qbase * 1024 + h * 64;
#pragma unroll
    for (int n = 0; n < 4; ++n)
#pragma unroll
        for (int r = 0; r < 4; ++r)
            op[(size_t)(hi * 4 + r) * 1024 + n * 16 + lo] = f2bf(oacc[n][r] * inv[r]);
}

// ---------------- host ----------------
extern "C" void kernel_launch(void* const* d_in, const int* in_sizes, int n_in,
                              void* d_out, int out_size, void* d_ws, size_t ws_size,
                              hipStream_t stream) {
    (void)in_sizes; (void)n_in; (void)out_size; (void)ws_size;
    const float* text  = (const float*)d_in[0];
    const float* image = (const float*)d_in[1];
    const int*   maski = (const int*)d_in[2];
    const float* w_qt = (const float*)d_in[3];  const float* b_qt = (const float*)d_in[4];
    const float* w_ki = (const float*)d_in[5];  const float* b_ki = (const float*)d_in[6];
    const float* w_vi = (const float*)d_in[7];  const float* b_vi = (const float*)d_in[8];
    const float* w_qi = (const float*)d_in[9];  const float* b_qi = (const float*)d_in[10];
    const float* w_kt = (const float*)d_in[11]; const float* b_kt = (const float*)d_in[12];
    const float* w_vt = (const float*)d_in[13]; const float* b_vt = (const float*)d_in[14];
    const float* w_ot = (const float*)d_in[15]; const float* b_ot = (const float*)d_in[16];
    const float* w_oi = (const float*)d_in[17]; const float* b_oi = (const float*)d_in[18];

    const int B = 16, T = 512, P = 576, D = 1024;
    const int MT = B * T;   // 8192
    const int MI = B * P;   // 9216

    char* wp = (char*)d_ws;
    auto alloc = [&](size_t bytes) { char* r = wp; wp += (bytes + 255) & ~(size_t)255; return r; };
    u16* Xt   = (u16*)alloc((size_t)MT * D * 2);
    u16* Xi   = (u16*)alloc((size_t)MI * D * 2);
    u16* Wt   = (u16*)alloc((size_t)3 * D * D * 2);
    u16* Wi   = (u16*)alloc((size_t)3 * D * D * 2);
    u16* Wot  = (u16*)alloc((size_t)D * D * 2);
    u16* Woi  = (u16*)alloc((size_t)D * D * 2);
    float* bt = (float*)alloc((size_t)3 * D * 4);
    float* bi = (float*)alloc((size_t)3 * D * 4);
    float* mbf = (float*)alloc((size_t)B * T * 4);
    u16* QKVt = (u16*)alloc((size_t)MT * 3 * D * 2);
    u16* QKVi = (u16*)alloc((size_t)MI * 3 * D * 2);
    u16* AttT = (u16*)alloc((size_t)MT * D * 2);
    u16* AttI = (u16*)alloc((size_t)MI * D * 2);

    auto cvt = [&](const float* s, u16* d, size_t n) {
        int n4 = (int)(n / 4);
        cvt_f32_bf16<<<(n4 + 255) / 256, 256, 0, stream>>>(s, d, n4);
    };
    cvt(text, Xt, (size_t)MT * D);
    cvt(image, Xi, (size_t)MI * D);
    cvt(w_qt, Wt,                   (size_t)D * D);
    cvt(w_kt, Wt + (size_t)D * D,   (size_t)D * D);
    cvt(w_vt, Wt + (size_t)2 * D * D, (size_t)D * D);
    cvt(w_qi, Wi,                   (size_t)D * D);
    cvt(w_ki, Wi + (size_t)D * D,   (size_t)D * D);
    cvt(w_vi, Wi + (size_t)2 * D * D, (size_t)D * D);
    cvt(w_ot, Wot, (size_t)D * D);
    cvt(w_oi, Woi, (size_t)D * D);
    hipMemcpyAsync(bt,         b_qt, D * 4, hipMemcpyDeviceToDevice, stream);
    hipMemcpyAsync(bt + D,     b_kt, D * 4, hipMemcpyDeviceToDevice, stream);
    hipMemcpyAsync(bt + 2 * D, b_vt, D * 4, hipMemcpyDeviceToDevice, stream);
    hipMemcpyAsync(bi,         b_qi, D * 4, hipMemcpyDeviceToDevice, stream);
    hipMemcpyAsync(bi + D,     b_ki, D * 4, hipMemcpyDeviceToDevice, stream);
    hipMemcpyAsync(bi + 2 * D, b_vi, D * 4, hipMemcpyDeviceToDevice, stream);
    mask_prep<<<(B * T + 255) / 256, 256, 0, stream>>>(maski, mbf, B * T);

    // fused QKV projections
    gemm_bt<1><<<dim3(3 * D / 128, MT / 128), 256, 0, stream>>>(Xt, Wt, bt, QKVt, MT, 3 * D, D, 3 * D);
    gemm_bt<1><<<dim3(3 * D / 128, MI / 128), 256, 0, stream>>>(Xi, Wi, bi, QKVi, MI, 3 * D, D, 3 * D);

    // text attends to image (no mask); image attends to text (mask on text keys)
    attn_fwd<0><<<dim3(T / 64, B * 16), 256, 0, stream>>>(QKVt, QKVi, nullptr, AttT, T, P);
    attn_fwd<1><<<dim3(P / 64, B * 16), 256, 0, stream>>>(QKVi, QKVt, mbf, AttI, P, T);

    // output projections (f32 out + bias)
    gemm_bt<0><<<dim3(D / 128, MT / 128), 256, 0, stream>>>(AttT, Wot, b_ot, d_out, MT, D, D, D);
    gemm_bt<0><<<dim3(D / 128, MI / 128), 256, 0, stream>>>(AttI, Woi, b_oi,
        (void*)((float*)d_out + (size_t)MT * D), MI, D, D, D);
}